// Round 15
// baseline (49.730 us; speedup 1.0000x reference)
//
#include <hip/hip_runtime.h>

#define PS    25
#define PADW  12
#define EPSV  (1.0f/255.0f)
#define WW    512
#define HH    512
#define NB    16
#define INV625 (1.0f/625.0f)

__device__ __forceinline__ int reflectI(int i, int n) {
    if (i < 0)  i = -i;
    if (i >= n) i = 2 * n - 2 - i;
    return i;
}

__device__ __forceinline__ float fastrcp(float x) {
    float y;
    asm("v_rcp_f32 %0, %1" : "=v"(y) : "v"(x));
    return y;
}

// Load 4 consecutive cols [gx0..gx0+3] of a row (x-reflection via reversed f4).
__device__ __forceinline__ float4 load_row_group(const float* __restrict__ row,
                                                 int gx0)
{
    if (gx0 >= 0 && gx0 <= WW - 4) {
        return *(const float4*)(row + gx0);
    } else if (gx0 < 0) {
        float4 v = *(const float4*)(row + (-gx0 - 3));
        return make_float4(v.w, v.z, v.y, v.x);
    } else {
        float4 v = *(const float4*)(row + (2*WW - 5 - gx0));
        return make_float4(v.w, v.z, v.y, v.x);
    }
}

// K1: horizontal 25-tap of m (channel mean) and s (channel mean of squares).
// One WAVE per half-row (256 out cols + 24 halo = 280). 4 px/lane.
// Wave-private LDS row buffer; NO __syncthreads anywhere.
__global__ __launch_bounds__(512, 8)
void kernH(const float* __restrict__ img,
           float* __restrict__ Hm, float* __restrict__ Hs)
{
    const int t    = threadIdx.x;
    const int w    = t >> 6;                 // wave 0..7
    const int l    = t & 63;                 // lane
    const int task = blockIdx.x * 8 + w;     // 0..16383
    const int half = task & 1;
    const int rowg = task >> 1;              // img*512 + row
    const int b    = rowg >> 9;
    const int row  = rowg & 511;

    __shared__ float bm[8][280];             // wave-private m row buffer
    __shared__ float bs[8][280];             // wave-private s row buffer

    const size_t plane = (size_t)WW * HH;
    const float* pR = img + (size_t)b * 3 * plane + (size_t)row * WW;
    const float* pG = pR + plane;
    const float* pB = pR + 2 * plane;

    // ---- load 70 f4-groups covering cols 256*half-12 .. 256*half+267 ----
    const int cbase = half * 256 - PADW;
#pragma unroll 2
    for (int g = l; g < 70; g += 64) {
        const int gx0 = cbase + 4 * g;
        float4 r4 = load_row_group(pR, gx0);
        float4 g4 = load_row_group(pG, gx0);
        float4 b4 = load_row_group(pB, gx0);
        float rr[4] = {r4.x, r4.y, r4.z, r4.w};
        float gg[4] = {g4.x, g4.y, g4.z, g4.w};
        float bb[4] = {b4.x, b4.y, b4.z, b4.w};
        float m[4], s[4];
#pragma unroll
        for (int j = 0; j < 4; ++j) {
            m[j] = (rr[j] + gg[j] + bb[j]) * (1.0f/3.0f);
            s[j] = fmaf(rr[j], rr[j], fmaf(gg[j], gg[j], bb[j]*bb[j])) * (1.0f/3.0f);
        }
        *(float4*)&bm[w][4*g] = make_float4(m[0], m[1], m[2], m[3]);
        *(float4*)&bs[w][4*g] = make_float4(s[0], s[1], s[2], s[3]);
    }
    // in-order per-wave DS pipe: compiler inserts lgkmcnt before dependent reads

    // ---- horizontal 25-tap window for this lane's 4 px (buffer 4l..4l+27) ----
    const float* mrow = &bm[w][4*l];
    const float* srow = &bs[w][4*l];
    const float4 m0 = *(const float4*)(mrow);
    const float4 s0 = *(const float4*)(srow);
    const float4 m6 = *(const float4*)(mrow + 24);
    const float4 s6 = *(const float4*)(srow + 24);
    float midm = 0.f, mids = 0.f;
#pragma unroll
    for (int i = 1; i <= 5; ++i) {
        float4 a = *(const float4*)(mrow + 4*i);
        float4 c = *(const float4*)(srow + 4*i);
        midm += (a.x + a.y) + (a.z + a.w);
        mids += (c.x + c.y) + (c.z + c.w);
    }
    float hm = (m0.x + m0.y) + (m0.z + m0.w) + midm + m6.x;
    float hs = (s0.x + s0.y) + (s0.z + s0.w) + mids + s6.x;

    const float oldm[3] = {m0.x, m0.y, m0.z};
    const float olds[3] = {s0.x, s0.y, s0.z};
    const float newm[3] = {m6.y, m6.z, m6.w};
    const float news[3] = {s6.y, s6.z, s6.w};

    float om[4], os[4];
#pragma unroll
    for (int j = 0; j < 4; ++j) {
        if (j > 0) {
            hm += newm[j-1] - oldm[j-1];
            hs += news[j-1] - olds[j-1];
        }
        om[j] = hm;
        os[j] = hs;
    }

    const size_t o = (size_t)rowg * WW + half * 256 + 4 * l;
    *(float4*)(Hm + o) = make_float4(om[0], om[1], om[2], om[3]);
    *(float4*)(Hs + o) = make_float4(os[0], os[1], os[2], os[3]);
}

// K2: vertical 25-tap running sum over H + sat + final score.
// thread = one column; 16-row strip; register sliding window; no LDS.
__global__ __launch_bounds__(256, 8)
void kernV(const float* __restrict__ img,
           const float* __restrict__ Hm, const float* __restrict__ Hs,
           float* __restrict__ out)
{
    const int t  = threadIdx.x;
    const int c  = blockIdx.x * 256 + t;     // 0..511
    const int y0 = blockIdx.y * 16;
    const int b  = blockIdx.z;

    const size_t plane = (size_t)WW * HH;
    const float* hm = Hm + (size_t)b * plane;
    const float* hs = Hs + (size_t)b * plane;
    const float* pR = img + (size_t)b * 3 * plane;
    const float* pG = pR + plane;
    const float* pB = pR + 2 * plane;
    float* ob = out + (size_t)b * plane;

    // prologue: window rows y0-12 .. y0+12
    float vm = 0.f, vs = 0.f;
#pragma unroll
    for (int k = -PADW; k <= PADW; ++k) {
        const int ry = reflectI(y0 + k, HH);
        vm += hm[((size_t)ry << 9) + c];
        vs += hs[((size_t)ry << 9) + c];
    }

#pragma unroll 2
    for (int y = y0; y < y0 + 16; ++y) {
        const size_t ro = ((size_t)y << 9) + c;
        const float r  = pR[ro];
        const float g  = pG[ro];
        const float bl = pB[ro];
        const float mx = fmaxf(r, fmaxf(g, bl));
        const float mn = fminf(r, fminf(g, bl));
        const float sat = (mx - mn + EPSV) * fastrcp(mx + EPSV);

        const float mean     = vm * INV625;
        const float msq      = vs * INV625;
        const float contrast = fmaf(-mean, mean, msq);
        const float expo     = fabsf(mean - 0.5f) + EPSV;
        ob[ro] = sat * contrast * fastrcp(expo);

        // slide window: +row y+13, -row y-12
        const int yn = reflectI(y + PADW + 1, HH);
        const int yo = reflectI(y - PADW, HH);
        vm += hm[((size_t)yn << 9) + c] - hm[((size_t)yo << 9) + c];
        vs += hs[((size_t)yn << 9) + c] - hs[((size_t)yo << 9) + c];
    }
}

extern "C" void kernel_launch(void* const* d_in, const int* in_sizes, int n_in,
                              void* d_out, int out_size, void* d_ws, size_t ws_size,
                              hipStream_t stream)
{
    const float* img = (const float*)d_in[0];
    float* out = (float*)d_out;

    const size_t plane_elems = (size_t)NB * HH * WW;   // 4 Mi elements
    float* Hm = (float*)d_ws;
    float* Hs = Hm + plane_elems;

    // K1: 16384 half-row wave-tasks / 8 waves per block = 2048 blocks
    kernH<<<dim3(2048, 1, 1), 512, 0, stream>>>(img, Hm, Hs);

    // K2: 2 col-halves x 32 row-strips x 16 images = 1024 blocks
    kernV<<<dim3(2, 32, NB), 256, 0, stream>>>(img, Hm, Hs, out);
}

// Round 16
// 39.454 us; speedup vs baseline: 1.2604x; 1.2604x over previous
//
#include <hip/hip_runtime.h>

#define PS     25
#define PADW   12
#define EPSV   (1.0f/255.0f)
#define WW     512
#define HH     512
#define NB     16
#define INV625 (1.0f/625.0f)

#define K1_TW   64
#define K1_TH   32
#define CHROWS  14            // rows per chunk; 4*14 = 56 halo rows exactly

__device__ __forceinline__ int reflectI(int i, int n) {
    if (i < 0)  i = -i;
    if (i >= n) i = 2 * n - 2 - i;
    return i;
}

__device__ __forceinline__ float fastrcp(float x) {
    float y;
    asm("v_rcp_f32 %0, %1" : "=v"(y) : "v"(x));
    return y;
}

// Load 4 consecutive cols [gx0..gx0+3] of a row (x-reflection via reversed f4).
__device__ __forceinline__ float4 load_row_group(const float* __restrict__ row,
                                                 int gx0)
{
    if (gx0 >= 0 && gx0 <= WW - 4) {
        return *(const float4*)(row + gx0);
    } else if (gx0 < 0) {
        float4 v = *(const float4*)(row + (-gx0 - 3));
        return make_float4(v.w, v.z, v.y, v.x);
    } else {
        float4 v = *(const float4*)(row + (2*WW - 5 - gx0));
        return make_float4(v.w, v.z, v.y, v.x);
    }
}

// K1: vertical 25-tap sums of m and s.
// Block = 64 cols x 32 out rows. Thread (c,k) owns col c, halo rows 14k..14k+13.
// Chunk-local prefix sums in registers; 3 disjoint accumulation passes build
// window sums in a 16 KB LDS tile. No raw m/s ever stored.
__global__ __launch_bounds__(256, 8)
void kernV(const float* __restrict__ img,
           float* __restrict__ Vm, float* __restrict__ Vs)
{
    const int t  = threadIdx.x;
    const int c  = t & 63;
    const int k  = t >> 6;
    const int x0 = blockIdx.x * K1_TW;
    const int y0 = blockIdx.y * K1_TH;
    const int b  = blockIdx.z;

    const size_t plane = (size_t)WW * HH;
    const float* pR = img + (size_t)b * 3 * plane;
    const float* pG = pR + plane;
    const float* pB = pR + 2 * plane;
    const int gx = x0 + c;

    // chunk-local prefix sums (registers)
    float pm[CHROWS], ps[CHROWS];
    float rm = 0.f, rs = 0.f;
#pragma unroll
    for (int i = 0; i < CHROWS; ++i) {
        int gy = reflectI(y0 - PADW + k * CHROWS + i, HH);
        size_t idx = ((size_t)gy << 9) + gx;
        float r  = pR[idx];
        float g  = pG[idx];
        float bl = pB[idx];
        rm += (r + g + bl) * (1.0f/3.0f);
        rs += fmaf(r, r, fmaf(g, g, bl*bl)) * (1.0f/3.0f);
        pm[i] = rm;
        ps[i] = rs;
    }

    __shared__ float Wm[K1_TH][64];
    __shared__ float Ws[K1_TH][64];

    // out row r's window = halo rows [r, r+24]; chunk k covers [14k, 14k+13].
    // Pass j: thread k handles rows r with floor(r/14) == k - j  -> per-pass
    // (r,c) writers are unique; barriers order the passes.
    const int kb = k * CHROWS;
#pragma unroll
    for (int j = 0; j < 3; ++j) {
        if (j) __syncthreads();
        const int r0 = kb - j * CHROWS;
#pragma unroll
        for (int i = 0; i < CHROWS; ++i) {
            const int r = r0 + i;
            if (r >= 0 && r < K1_TH) {
                const int lo = (kb > r) ? kb : r;
                const int hi = (kb + CHROWS - 1 < r + PS - 1) ? kb + CHROWS - 1
                                                              : r + PS - 1;
                if (hi >= lo) {
                    const int hiL = hi - kb;
                    const int loL = lo - kb;
                    float cm = pm[hiL] - (loL > 0 ? pm[loL-1] : 0.f);
                    float cs = ps[hiL] - (loL > 0 ? ps[loL-1] : 0.f);
                    if (j == 0) { Wm[r][c] = cm;  Ws[r][c] = cs;  }
                    else        { Wm[r][c] += cm; Ws[r][c] += cs; }
                }
            }
        }
    }
    __syncthreads();

    // store 32x64 tile: 512 float4 per array, 2 per thread, coalesced
    float* vmp = Vm + (size_t)b * plane;
    float* vsp = Vs + (size_t)b * plane;
#pragma unroll
    for (int q = 0; q < 2; ++q) {
        int idx = t + q * 256;      // 0..511
        int row = idx >> 4;         // 0..31
        int g4  = idx & 15;         // 0..15
        float4 vm4 = *(const float4*)&Wm[row][g4 * 4];
        float4 vs4 = *(const float4*)&Ws[row][g4 * 4];
        size_t o = ((size_t)(y0 + row) << 9) + x0 + g4 * 4;
        *(float4*)(vmp + o) = vm4;
        *(float4*)(vsp + o) = vs4;
    }
}

// K2: horizontal 25-tap over Vm/Vs + sat + final score.
// One WAVE per half-row; wave-private LDS buffers; NO barriers.
__global__ __launch_bounds__(512, 8)
void kernHF(const float* __restrict__ img,
            const float* __restrict__ Vm, const float* __restrict__ Vs,
            float* __restrict__ out)
{
    const int t    = threadIdx.x;
    const int w    = t >> 6;
    const int l    = t & 63;
    const int task = blockIdx.x * 8 + w;   // 0..16383
    const int half = task & 1;
    const int rowg = task >> 1;            // b*512 + row
    const int b    = rowg >> 9;
    const int row  = rowg & 511;

    __shared__ float bm[8][280];           // wave-private vertical-sum buffers
    __shared__ float bs[8][280];

    const size_t plane = (size_t)WW * HH;
    const float* vmr = Vm + (size_t)b * plane + ((size_t)row << 9);
    const float* vsr = Vs + (size_t)b * plane + ((size_t)row << 9);
    const int cbase = half * 256 - PADW;

    // load 70 f4-groups covering cols cbase .. cbase+279 (x-reflect at edges)
#pragma unroll 2
    for (int g = l; g < 70; g += 64) {
        const int gx0 = cbase + 4 * g;
        *(float4*)&bm[w][4*g] = load_row_group(vmr, gx0);
        *(float4*)&bs[w][4*g] = load_row_group(vsr, gx0);
    }

    // sat loads at this lane's 4 output cols (independent of LDS)
    const float* pR = img + (size_t)b * 3 * plane + ((size_t)row << 9);
    const float* pG = pR + plane;
    const float* pB = pR + 2 * plane;
    const int xo = half * 256 + 4 * l;
    const float4 ra = *(const float4*)(pR + xo);
    const float4 ga = *(const float4*)(pG + xo);
    const float4 ba = *(const float4*)(pB + xo);

    // horizontal 25-tap streaming window over buf[4l .. 4l+27]
    const float* mrow = &bm[w][4*l];
    const float* srow = &bs[w][4*l];
    const float4 m0 = *(const float4*)(mrow);
    const float4 s0 = *(const float4*)(srow);
    const float4 m6 = *(const float4*)(mrow + 24);
    const float4 s6 = *(const float4*)(srow + 24);
    float midm = 0.f, mids = 0.f;
#pragma unroll
    for (int i = 1; i <= 5; ++i) {
        float4 a = *(const float4*)(mrow + 4*i);
        float4 cc = *(const float4*)(srow + 4*i);
        midm += (a.x + a.y) + (a.z + a.w);
        mids += (cc.x + cc.y) + (cc.z + cc.w);
    }
    float hm = (m0.x + m0.y) + (m0.z + m0.w) + midm + m6.x;
    float hs = (s0.x + s0.y) + (s0.z + s0.w) + mids + s6.x;

    const float oldm[3] = {m0.x, m0.y, m0.z};
    const float olds[3] = {s0.x, s0.y, s0.z};
    const float newm[3] = {m6.y, m6.z, m6.w};
    const float news[3] = {s6.y, s6.z, s6.w};
    const float rr[4] = {ra.x, ra.y, ra.z, ra.w};
    const float gg[4] = {ga.x, ga.y, ga.z, ga.w};
    const float bb[4] = {ba.x, ba.y, ba.z, ba.w};

    float sc[4];
#pragma unroll
    for (int j = 0; j < 4; ++j) {
        if (j > 0) {
            hm += newm[j-1] - oldm[j-1];
            hs += news[j-1] - olds[j-1];
        }
        float mx = fmaxf(rr[j], fmaxf(gg[j], bb[j]));
        float mn = fminf(rr[j], fminf(gg[j], bb[j]));
        float sat = (mx - mn + EPSV) * fastrcp(mx + EPSV);

        float mean     = hm * INV625;
        float msq      = hs * INV625;
        float contrast = fmaf(-mean, mean, msq);
        float expo     = fabsf(mean - 0.5f) + EPSV;
        sc[j] = sat * contrast * fastrcp(expo);
    }
    float* orow = out + ((size_t)b * HH + row) * WW + xo;
    *(float4*)orow = make_float4(sc[0], sc[1], sc[2], sc[3]);
}

extern "C" void kernel_launch(void* const* d_in, const int* in_sizes, int n_in,
                              void* d_out, int out_size, void* d_ws, size_t ws_size,
                              hipStream_t stream)
{
    const float* img = (const float*)d_in[0];
    float* out = (float*)d_out;

    const size_t plane_elems = (size_t)NB * HH * WW;   // 4 Mi elements
    float* Vm = (float*)d_ws;
    float* Vs = Vm + plane_elems;

    // K1: 8 x-tiles x 16 y-tiles x 16 images = 2048 blocks x 256 threads
    kernV<<<dim3(WW / K1_TW, HH / K1_TH, NB), 256, 0, stream>>>(img, Vm, Vs);

    // K2: 16384 half-row wave-tasks / 8 waves = 2048 blocks x 512 threads
    kernHF<<<dim3(2048, 1, 1), 512, 0, stream>>>(img, Vm, Vs, out);
}